// Round 4
// baseline (536.441 us; speedup 1.0000x reference)
//
#include <hip/hip_runtime.h>
#include <hip/hip_bf16.h>
#include <stdint.h>

// FusedLinearCrossEntropyLoss on MI355X (gfx950)
// loss = mean_i( logsumexp_j(x_i . w_j + b_j) - (x_i . w_t(i) + b_t(i)) )
//
// R4: A-operand (X rows, 4 MB fp8, L2-resident) loaded DIRECTLY from global as
//     per-lane 32-B fragments -> only W goes through LDS. Halves LDS traffic +
//     staging drain. B chunk-pair layout reverted to R2's zero-conflict pattern
//     (pair at positions q, q^4 via bit-rotated chunk placement).

typedef float f16v __attribute__((ext_vector_type(16)));
typedef int v8i __attribute__((ext_vector_type(8)));

#define GLD16(g, l) __builtin_amdgcn_global_load_lds(                      \
    (__attribute__((address_space(1))) void*)(g),                          \
    (__attribute__((address_space(3))) void*)(l), 16, 0, 0)

__device__ __forceinline__ unsigned pk_fp8(float4 v) {
  int w = 0;
  w = __builtin_amdgcn_cvt_pk_fp8_f32(v.x, v.y, w, false);  // bytes 0,1
  w = __builtin_amdgcn_cvt_pk_fp8_f32(v.z, v.w, w, true);   // bytes 2,3
  return (unsigned)w;
}

// fp32 -> fp8 e4m3 (OCP), 16 elements per thread
__global__ __launch_bounds__(256) void cast_fp8_k(const float4* __restrict__ in,
                                                  uint4* __restrict__ out, long n16) {
  long i = (long)blockIdx.x * blockDim.x + threadIdx.x;
  long stride = (long)gridDim.x * blockDim.x;
  for (; i < n16; i += stride) {
    float4 v0 = in[i * 4 + 0], v1 = in[i * 4 + 1];
    float4 v2 = in[i * 4 + 2], v3 = in[i * 4 + 3];
    uint4 o;
    o.x = pk_fp8(v0); o.y = pk_fp8(v1); o.z = pk_fp8(v2); o.w = pk_fp8(v3);
    out[i] = o;
  }
}

// One block per row: x_y[row] = x[row] . W[safe_t] + bias[safe_t]  (fp32, exact)
__global__ __launch_bounds__(256) void xy_k(const float* __restrict__ x,
                                            const float* __restrict__ w,
                                            const float* __restrict__ bias,
                                            const int* __restrict__ tgt,
                                            float* __restrict__ xy, int H, int V) {
  int row = blockIdx.x;
  int t = tgt[row];
  int st = min(max(t, 0), V - 1);
  const float4* xr = (const float4*)(x + (long)row * H);
  const float4* wr = (const float4*)(w + (long)st * H);
  float s = 0.f;
  int n4 = H >> 2;
  for (int i = threadIdx.x; i < n4; i += 256) {
    float4 a = xr[i], b = wr[i];
    s += a.x * b.x + a.y * b.y + a.z * b.z + a.w * b.w;
  }
  for (int off = 32; off; off >>= 1) s += __shfl_down(s, off, 64);
  __shared__ float sm[4];
  if ((threadIdx.x & 63) == 0) sm[threadIdx.x >> 6] = s;
  __syncthreads();
  if (threadIdx.x == 0) xy[row] = sm[0] + sm[1] + sm[2] + sm[3] + bias[st];
}

// 128x128 tile fp8 GEMM (BK=128), 4 waves in 2x2, each wave 2x2 of 32x32x64.
// B (W tile) through XOR-swizzled LDS; chunk c of row r stored at position
// pos(c)^(r&7) with pos(c) = (c>>1) | ((c&1)<<2)  -> the k-pair (2q,2q+1) sits
// at positions q and q^4 (R2's verified conflict-free read pattern).
// A fragments read directly from global (L2-hot).
// Epilogue: partials[bn][row] = sum_cols exp(logit + bias).
__global__ __launch_bounds__(256)
void gemm_sumexp(const char* __restrict__ Xb, const char* __restrict__ Wb,
                 const float* __restrict__ bias, float* __restrict__ partials,
                 int H, int BT) {
  __shared__ __align__(16) char Bs[16384];   // 128 rows x 128 fp8
  __shared__ float rowsum[2][128];

  const int tid = threadIdx.x;
  const int w = tid >> 6, lane = tid & 63;
  const int wr = w >> 1, wc = w & 1;
  const int l32 = lane & 31, kh = lane >> 5;
  const int m0 = blockIdx.x * 128, n0 = blockIdx.y * 128;

  f16v acc[2][2];
#pragma unroll
  for (int mi = 0; mi < 2; mi++)
#pragma unroll
    for (int ni = 0; ni < 2; ni++)
#pragma unroll
      for (int r = 0; r < 16; r++) acc[mi][ni][r] = 0.f;

  // --- B staging: thread t covers row sr(+32j), LDS slot sp; global chunk
  //     c = inv_pos(sp ^ (sr&7)), inv_pos(p) = ((p&3)<<1) | (p>>2)
  const int sr = tid >> 3, sp = tid & 7;
  const int spx = sp ^ (sr & 7);
  const int sc = ((spx & 3) << 1) | (spx >> 2);
  const char* gB = Wb + (long)(n0 + sr) * H + sc * 16;
  char* lB = Bs + tid * 16;

  // --- A fragment source: lane reads row m0 + wr*64 + mi*32 + l32, 32 B at
  //     k = k0 + s*64 + kh*32
  const char* gA = Xb + (long)(m0 + wr * 64 + l32) * H + kh * 32;

  const int rx = l32 & 7;
  const int bbase = (wc * 64 + l32) * 128;     // ni adds +4096

  for (int k0 = 0; k0 < H; k0 += 128) {
    // A fragments for this K-tile: no LDS dependency, issue before barrier
    v8i a[2][2];
#pragma unroll
    for (int s = 0; s < 2; s++)
#pragma unroll
      for (int mi = 0; mi < 2; mi++)
        a[s][mi] = *(const v8i*)(gA + (long)mi * 32 * H + k0 + s * 64);

    __syncthreads();  // previous compute done before overwriting Bs
#pragma unroll
    for (int j = 0; j < 4; j++)
      GLD16(gB + (long)j * 32 * H + k0, lB + j * 4096);
    asm volatile("s_waitcnt vmcnt(0)" ::: "memory");
    __syncthreads();

#pragma unroll
    for (int s = 0; s < 2; s++) {              // two K=64 sub-steps
      const int q = s * 2 + kh;                // k-pair index 0..3
      const int o0 = (q ^ rx) * 16;
      const int o1 = o0 ^ 64;                  // position q^4
      v8i b[2];
#pragma unroll
      for (int ni = 0; ni < 2; ni++) {
        int4 lo = *(const int4*)(Bs + bbase + ni * 4096 + o0);
        int4 hi = *(const int4*)(Bs + bbase + ni * 4096 + o1);
        v8i t;
        t[0] = lo.x; t[1] = lo.y; t[2] = lo.z; t[3] = lo.w;
        t[4] = hi.x; t[5] = hi.y; t[6] = hi.z; t[7] = hi.w;
        b[ni] = t;
      }
#pragma unroll
      for (int mi = 0; mi < 2; mi++)
#pragma unroll
        for (int ni = 0; ni < 2; ni++)
          acc[mi][ni] = __builtin_amdgcn_mfma_scale_f32_32x32x64_f8f6f4(
              a[s][mi], b[ni], acc[mi][ni], 0 /*A=fp8*/, 0 /*B=fp8*/,
              0, 127 /*scale_a = 1.0*/, 0, 127 /*scale_b = 1.0*/);
    }
  }

  // ---- epilogue: per-row sum of exp(logit + bias) ----
  // C/D 32x32 layout: col = lane&31, row = (reg&3) + 8*(reg>>2) + 4*(lane>>5)
  float bv[2];
  bv[0] = bias[n0 + wc * 64 + l32];
  bv[1] = bias[n0 + wc * 64 + 32 + l32];

#pragma unroll
  for (int mi = 0; mi < 2; mi++) {
    float p[16];
#pragma unroll
    for (int r = 0; r < 16; r++) p[r] = 0.f;
#pragma unroll
    for (int ni = 0; ni < 2; ni++)
#pragma unroll
      for (int r = 0; r < 16; r++) p[r] += __expf(acc[mi][ni][r] + bv[ni]);
    // reduce across the 32 columns (lanes within each 32-group)
#pragma unroll
    for (int off = 1; off < 32; off <<= 1)
#pragma unroll
      for (int r = 0; r < 16; r++) p[r] += __shfl_xor(p[r], off, 32);
    if (l32 == 0) {
#pragma unroll
      for (int r = 0; r < 16; r++)
        rowsum[wc][wr * 64 + mi * 32 + (r & 3) + 8 * (r >> 2) + 4 * kh] = p[r];
    }
  }
  __syncthreads();
  if (tid < 128)
    partials[(long)blockIdx.y * BT + m0 + tid] = rowsum[0][tid] + rowsum[1][tid];
}

// per-row: lse - x_y ; block partial sums
__global__ __launch_bounds__(256)
void row_reduce(const float* __restrict__ partials, const float* __restrict__ xy,
                const int* __restrict__ tgt, float* __restrict__ bsum,
                float* __restrict__ bcnt, int BT, int nCB) {
  int row = blockIdx.x * 256 + threadIdx.x;
  float S = 0.f;
  for (int b = 0; b < nCB; b++) S += partials[(long)b * BT + row];
  int t = tgt[row];
  bool valid = (t != -100);
  float pr = valid ? (logf(S) - xy[row]) : 0.f;
  float c = valid ? 1.f : 0.f;
  for (int off = 32; off; off >>= 1) {
    pr += __shfl_down(pr, off, 64);
    c += __shfl_down(c, off, 64);
  }
  __shared__ float sp[4], sc[4];
  if ((threadIdx.x & 63) == 0) {
    sp[threadIdx.x >> 6] = pr;
    sc[threadIdx.x >> 6] = c;
  }
  __syncthreads();
  if (threadIdx.x == 0) {
    bsum[blockIdx.x] = sp[0] + sp[1] + sp[2] + sp[3];
    bcnt[blockIdx.x] = sc[0] + sc[1] + sc[2] + sc[3];
  }
}

__global__ void finalize(const float* __restrict__ bsum, const float* __restrict__ bcnt,
                         float* __restrict__ out, int nb) {
  float s = 0.f, c = 0.f;
  for (int i = threadIdx.x; i < nb; i += 64) { s += bsum[i]; c += bcnt[i]; }
  for (int off = 32; off; off >>= 1) {
    s += __shfl_down(s, off, 64);
    c += __shfl_down(c, off, 64);
  }
  if (threadIdx.x == 0) out[0] = s / c;
}

extern "C" void kernel_launch(void* const* d_in, const int* in_sizes, int n_in,
                              void* d_out, int out_size, void* d_ws, size_t ws_size,
                              hipStream_t stream) {
  const float* x = (const float*)d_in[0];
  const int* tgt = (const int*)d_in[1];
  const float* w = (const float*)d_in[2];
  const float* bias = (const float*)d_in[3];
  float* out = (float*)d_out;

  const int BT = in_sizes[1];            // 4096
  const int V = in_sizes[3];             // 32000
  const int H = in_sizes[0] / BT;        // 1024
  const int nCB = V / 128;               // 250 column blocks

  char* ws = (char*)d_ws;
  const long wb_bytes = (long)V * H;     // fp8: 1 B/elem
  const long xb_bytes = (long)BT * H;
  char* Wb = ws;
  char* Xb = ws + wb_bytes;
  float* partials = (float*)(ws + wb_bytes + xb_bytes);
  float* xy = partials + (long)nCB * BT;
  float* bsum = xy + BT;
  float* bcnt = bsum + (BT / 256);

  cast_fp8_k<<<8192, 256, 0, stream>>>((const float4*)w, (uint4*)Wb, (long)V * H / 16);
  cast_fp8_k<<<1024, 256, 0, stream>>>((const float4*)x, (uint4*)Xb, (long)BT * H / 16);
  xy_k<<<BT, 256, 0, stream>>>(x, w, bias, tgt, xy, H, V);
  // grid.x = row-blocks (fast-varying) so consecutive blocks share the W tile in L2
  dim3 grid(BT / 128, nCB);
  gemm_sumexp<<<grid, 256, 0, stream>>>(Xb, Wb, bias, partials, H, BT);
  row_reduce<<<BT / 256, 256, 0, stream>>>(partials, xy, tgt, bsum, bcnt, BT, nCB);
  finalize<<<1, 64, 0, stream>>>(bsum, bcnt, out, BT / 256);
}

// Round 5
// 442.376 us; speedup vs baseline: 1.2126x; 1.2126x over previous
//
#include <hip/hip_runtime.h>
#include <hip/hip_bf16.h>
#include <stdint.h>

// FusedLinearCrossEntropyLoss on MI355X (gfx950)
// loss = mean_i( logsumexp_j(x_i . w_j + b_j) - (x_i . w_t(i) + b_t(i)) )
//
// R5: back to R3's all-LDS staging (R4's direct-global A regressed: scattered
//     32-B strided loads). Register blocking raised to 4x2 per wave
//     (wave tile 128x64, block tile 256x128) -> LDS reads/MFMA 2.0 -> 1.5,
//     staging writes/FLOP 0.75x, 16 MFMAs per barrier drain.

typedef float f16v __attribute__((ext_vector_type(16)));
typedef int v8i __attribute__((ext_vector_type(8)));

#define GLD16(g, l) __builtin_amdgcn_global_load_lds(                      \
    (__attribute__((address_space(1))) void*)(g),                          \
    (__attribute__((address_space(3))) void*)(l), 16, 0, 0)

__device__ __forceinline__ unsigned pk_fp8(float4 v) {
  int w = 0;
  w = __builtin_amdgcn_cvt_pk_fp8_f32(v.x, v.y, w, false);  // bytes 0,1
  w = __builtin_amdgcn_cvt_pk_fp8_f32(v.z, v.w, w, true);   // bytes 2,3
  return (unsigned)w;
}

// fp32 -> fp8 e4m3 (OCP), 16 elements per thread
__global__ __launch_bounds__(256) void cast_fp8_k(const float4* __restrict__ in,
                                                  uint4* __restrict__ out, long n16) {
  long i = (long)blockIdx.x * blockDim.x + threadIdx.x;
  long stride = (long)gridDim.x * blockDim.x;
  for (; i < n16; i += stride) {
    float4 v0 = in[i * 4 + 0], v1 = in[i * 4 + 1];
    float4 v2 = in[i * 4 + 2], v3 = in[i * 4 + 3];
    uint4 o;
    o.x = pk_fp8(v0); o.y = pk_fp8(v1); o.z = pk_fp8(v2); o.w = pk_fp8(v3);
    out[i] = o;
  }
}

// One block per row: x_y[row] = x[row] . W[safe_t] + bias[safe_t]  (fp32, exact)
__global__ __launch_bounds__(256) void xy_k(const float* __restrict__ x,
                                            const float* __restrict__ w,
                                            const float* __restrict__ bias,
                                            const int* __restrict__ tgt,
                                            float* __restrict__ xy, int H, int V) {
  int row = blockIdx.x;
  int t = tgt[row];
  int st = min(max(t, 0), V - 1);
  const float4* xr = (const float4*)(x + (long)row * H);
  const float4* wr = (const float4*)(w + (long)st * H);
  float s = 0.f;
  int n4 = H >> 2;
  for (int i = threadIdx.x; i < n4; i += 256) {
    float4 a = xr[i], b = wr[i];
    s += a.x * b.x + a.y * b.y + a.z * b.z + a.w * b.w;
  }
  for (int off = 32; off; off >>= 1) s += __shfl_down(s, off, 64);
  __shared__ float sm[4];
  if ((threadIdx.x & 63) == 0) sm[threadIdx.x >> 6] = s;
  __syncthreads();
  if (threadIdx.x == 0) xy[row] = sm[0] + sm[1] + sm[2] + sm[3] + bias[st];
}

// 256x128 block tile, BK=128 fp8. 4 waves in 2x2; each wave = 128x64 via a
// 4x2 grid of 32x32x64 scaled MFMAs (acc 128 VGPRs). LDS rows are 128 B;
// chunk c of row r stored at position c^(r&7) (R2/R3 swizzle). A=32 KB,
// B=16 KB staged via global_load_lds width-16.
// Epilogue: partials[bn][row] = sum_cols exp(logit + bias).
__global__ __launch_bounds__(256, 2)
void gemm_sumexp(const char* __restrict__ Xb, const char* __restrict__ Wb,
                 const float* __restrict__ bias, float* __restrict__ partials,
                 int H, int BT) {
  __shared__ __align__(16) char As[32768];   // 256 rows x 128 fp8
  __shared__ __align__(16) char Bs[16384];   // 128 rows x 128 fp8
  __shared__ float rowsum[2][256];

  const int tid = threadIdx.x;
  const int w = tid >> 6, lane = tid & 63;
  const int wr = w >> 1, wc = w & 1;
  const int l32 = lane & 31, kh = lane >> 5;
  const int m0 = blockIdx.x * 256, n0 = blockIdx.y * 128;

  f16v acc[4][2];
#pragma unroll
  for (int mi = 0; mi < 4; mi++)
#pragma unroll
    for (int ni = 0; ni < 2; ni++)
#pragma unroll
      for (int r = 0; r < 16; r++) acc[mi][ni][r] = 0.f;

  // staging: thread t covers row sr(+32j), LDS slot sp; global chunk sq=sp^(sr&7)
  const int sr = tid >> 3, sp = tid & 7, sq = sp ^ (sr & 7);
  const char* gA = Xb + (long)(m0 + sr) * H + sq * 16;
  const char* gB = Wb + (long)(n0 + sr) * H + sq * 16;
  char* lA = As + tid * 16;
  char* lB = Bs + tid * 16;

  const int rx = l32 & 7;
  const int abase = (wr * 128 + l32) * 128;    // mi adds +4096 (32 rows)
  const int bbase = (wc * 64 + l32) * 128;     // ni adds +4096

  for (int k0 = 0; k0 < H; k0 += 128) {
    __syncthreads();  // previous compute done before overwriting LDS
#pragma unroll
    for (int j = 0; j < 8; j++)
      GLD16(gA + (long)j * 32 * H + k0, lA + j * 4096);
#pragma unroll
    for (int j = 0; j < 4; j++)
      GLD16(gB + (long)j * 32 * H + k0, lB + j * 4096);
    asm volatile("s_waitcnt vmcnt(0)" ::: "memory");
    __syncthreads();

#pragma unroll
    for (int s = 0; s < 2; s++) {              // two K=64 sub-steps
      const int c0 = s * 4 + kh * 2;           // lane's first 16-B k-chunk
      const int o0 = (c0 ^ rx) * 16;
      const int o1 = o0 ^ 16;                  // chunk c0+1 (c0 even)
      v8i a[4], b[2];
#pragma unroll
      for (int mi = 0; mi < 4; mi++) {
        int4 lo = *(const int4*)(As + abase + mi * 4096 + o0);
        int4 hi = *(const int4*)(As + abase + mi * 4096 + o1);
        v8i t;
        t[0] = lo.x; t[1] = lo.y; t[2] = lo.z; t[3] = lo.w;
        t[4] = hi.x; t[5] = hi.y; t[6] = hi.z; t[7] = hi.w;
        a[mi] = t;
      }
#pragma unroll
      for (int ni = 0; ni < 2; ni++) {
        int4 lo = *(const int4*)(Bs + bbase + ni * 4096 + o0);
        int4 hi = *(const int4*)(Bs + bbase + ni * 4096 + o1);
        v8i t;
        t[0] = lo.x; t[1] = lo.y; t[2] = lo.z; t[3] = lo.w;
        t[4] = hi.x; t[5] = hi.y; t[6] = hi.z; t[7] = hi.w;
        b[ni] = t;
      }
#pragma unroll
      for (int mi = 0; mi < 4; mi++)
#pragma unroll
        for (int ni = 0; ni < 2; ni++)
          acc[mi][ni] = __builtin_amdgcn_mfma_scale_f32_32x32x64_f8f6f4(
              a[mi], b[ni], acc[mi][ni], 0 /*A=fp8*/, 0 /*B=fp8*/,
              0, 127 /*scale_a = 1.0*/, 0, 127 /*scale_b = 1.0*/);
    }
  }

  // ---- epilogue: per-row sum of exp(logit + bias) ----
  // C/D 32x32 layout: col = lane&31, row = (reg&3) + 8*(reg>>2) + 4*(lane>>5)
  float bv[2];
  bv[0] = bias[n0 + wc * 64 + l32];
  bv[1] = bias[n0 + wc * 64 + 32 + l32];

#pragma unroll
  for (int mi = 0; mi < 4; mi++) {
    float p[16];
#pragma unroll
    for (int r = 0; r < 16; r++) p[r] = 0.f;
#pragma unroll
    for (int ni = 0; ni < 2; ni++)
#pragma unroll
      for (int r = 0; r < 16; r++) p[r] += __expf(acc[mi][ni][r] + bv[ni]);
    // reduce across the 32 columns (lanes within each 32-group)
#pragma unroll
    for (int off = 1; off < 32; off <<= 1)
#pragma unroll
      for (int r = 0; r < 16; r++) p[r] += __shfl_xor(p[r], off, 32);
    if (l32 == 0) {
#pragma unroll
      for (int r = 0; r < 16; r++)
        rowsum[wc][wr * 128 + mi * 32 + (r & 3) + 8 * (r >> 2) + 4 * kh] = p[r];
    }
  }
  __syncthreads();
  partials[(long)blockIdx.y * BT + m0 + tid] = rowsum[0][tid] + rowsum[1][tid];
}

// per-row: lse - x_y ; block partial sums
__global__ __launch_bounds__(256)
void row_reduce(const float* __restrict__ partials, const float* __restrict__ xy,
                const int* __restrict__ tgt, float* __restrict__ bsum,
                float* __restrict__ bcnt, int BT, int nCB) {
  int row = blockIdx.x * 256 + threadIdx.x;
  float S = 0.f;
  for (int b = 0; b < nCB; b++) S += partials[(long)b * BT + row];
  int t = tgt[row];
  bool valid = (t != -100);
  float pr = valid ? (logf(S) - xy[row]) : 0.f;
  float c = valid ? 1.f : 0.f;
  for (int off = 32; off; off >>= 1) {
    pr += __shfl_down(pr, off, 64);
    c += __shfl_down(c, off, 64);
  }
  __shared__ float sp[4], sc[4];
  if ((threadIdx.x & 63) == 0) {
    sp[threadIdx.x >> 6] = pr;
    sc[threadIdx.x >> 6] = c;
  }
  __syncthreads();
  if (threadIdx.x == 0) {
    bsum[blockIdx.x] = sp[0] + sp[1] + sp[2] + sp[3];
    bcnt[blockIdx.x] = sc[0] + sc[1] + sc[2] + sc[3];
  }
}

__global__ void finalize(const float* __restrict__ bsum, const float* __restrict__ bcnt,
                         float* __restrict__ out, int nb) {
  float s = 0.f, c = 0.f;
  for (int i = threadIdx.x; i < nb; i += 64) { s += bsum[i]; c += bcnt[i]; }
  for (int off = 32; off; off >>= 1) {
    s += __shfl_down(s, off, 64);
    c += __shfl_down(c, off, 64);
  }
  if (threadIdx.x == 0) out[0] = s / c;
}

extern "C" void kernel_launch(void* const* d_in, const int* in_sizes, int n_in,
                              void* d_out, int out_size, void* d_ws, size_t ws_size,
                              hipStream_t stream) {
  const float* x = (const float*)d_in[0];
  const int* tgt = (const int*)d_in[1];
  const float* w = (const float*)d_in[2];
  const float* bias = (const float*)d_in[3];
  float* out = (float*)d_out;

  const int BT = in_sizes[1];            // 4096
  const int V = in_sizes[3];             // 32000
  const int H = in_sizes[0] / BT;        // 1024
  const int nCB = V / 128;               // 250 column blocks

  char* ws = (char*)d_ws;
  const long wb_bytes = (long)V * H;     // fp8: 1 B/elem
  const long xb_bytes = (long)BT * H;
  char* Wb = ws;
  char* Xb = ws + wb_bytes;
  float* partials = (float*)(ws + wb_bytes + xb_bytes);
  float* xy = partials + (long)nCB * BT;
  float* bsum = xy + BT;
  float* bcnt = bsum + (BT / 256);

  cast_fp8_k<<<8192, 256, 0, stream>>>((const float4*)w, (uint4*)Wb, (long)V * H / 16);
  cast_fp8_k<<<1024, 256, 0, stream>>>((const float4*)x, (uint4*)Xb, (long)BT * H / 16);
  xy_k<<<BT, 256, 0, stream>>>(x, w, bias, tgt, xy, H, V);
  // grid.x = row-blocks (fast-varying) so consecutive blocks share the W tile in L2
  dim3 grid(BT / 256, nCB);
  gemm_sumexp<<<grid, 256, 0, stream>>>(Xb, Wb, bias, partials, H, BT);
  row_reduce<<<BT / 256, 256, 0, stream>>>(partials, xy, tgt, bsum, bcnt, BT, nCB);
  finalize<<<1, 64, 0, stream>>>(bsum, bcnt, out, BT / 256);
}

// Round 6
// 421.407 us; speedup vs baseline: 1.2730x; 1.0498x over previous
//
#include <hip/hip_runtime.h>
#include <hip/hip_bf16.h>
#include <stdint.h>

// FusedLinearCrossEntropyLoss on MI355X (gfx950)
// loss = mean_i( logsumexp_j(x_i . w_j + b_j) - (x_i . w_t(i) + b_t(i)) )
//
// R6: NO-LDS GEMM. Cast kernels pre-swizzle X,W (fp32->fp8) into MFMA
//     fragment-native 2KB chunks (32 rows x 64 k). The K-loop loads fragments
//     straight global->VGPR (dense dwordx4, L1/L2-hot) and runs MFMAs with no
//     __syncthreads / no vmcnt(0) drains — the structural stall of the
//     LDS-staged 2-barrier loop (R3/R5: ~60% idle) is removed.
//
// Chunk layout: chunk c = R*16 + g (R = 32-row block, g = 64-wide k group).
// Within chunk: half h in {0,1}, lane λ in 0..63, byte j in 0..15:
//   data[c*2048 + h*1024 + λ*16 + j] = M[R*32 + (λ&31)][g*64 + (λ>>5)*32 + h*16 + j]
// A wave's 32-B/lane MFMA fragment = two dense 1KB dwordx4 loads.

typedef float f16v __attribute__((ext_vector_type(16)));
typedef int v8i __attribute__((ext_vector_type(8)));

__device__ __forceinline__ unsigned pk_fp8(float4 v) {
  int w = 0;
  w = __builtin_amdgcn_cvt_pk_fp8_f32(v.x, v.y, w, false);  // bytes 0,1
  w = __builtin_amdgcn_cvt_pk_fp8_f32(v.z, v.w, w, true);   // bytes 2,3
  return (unsigned)w;
}

// fp32 [N x 1024] -> fp8 fragment-swizzled chunks. One thread = 16 out bytes.
__global__ __launch_bounds__(256) void cast_swz_k(const float* __restrict__ in,
                                                  uint4* __restrict__ out,
                                                  long n16) {
  long t = (long)blockIdx.x * blockDim.x + threadIdx.x;
  long stride = (long)gridDim.x * blockDim.x;
  for (; t < n16; t += stride) {
    long o = t * 16;
    int c = (int)(o >> 11);
    int rem = (int)(o & 2047);
    int h = rem >> 10;
    int lam = (rem >> 4) & 63;
    int row = (c >> 4) * 32 + (lam & 31);
    int k = (c & 15) * 64 + (lam >> 5) * 32 + h * 16;
    const float4* src = (const float4*)(in + (long)row * 1024 + k);
    uint4 oo;
    oo.x = pk_fp8(src[0]); oo.y = pk_fp8(src[1]);
    oo.z = pk_fp8(src[2]); oo.w = pk_fp8(src[3]);
    out[t] = oo;
  }
}

// One block per row: x_y[row] = x[row] . W[safe_t] + bias[safe_t]  (fp32, exact)
__global__ __launch_bounds__(256) void xy_k(const float* __restrict__ x,
                                            const float* __restrict__ w,
                                            const float* __restrict__ bias,
                                            const int* __restrict__ tgt,
                                            float* __restrict__ xy, int H, int V) {
  int row = blockIdx.x;
  int t = tgt[row];
  int st = min(max(t, 0), V - 1);
  const float4* xr = (const float4*)(x + (long)row * H);
  const float4* wr = (const float4*)(w + (long)st * H);
  float s = 0.f;
  int n4 = H >> 2;
  for (int i = threadIdx.x; i < n4; i += 256) {
    float4 a = xr[i], b = wr[i];
    s += a.x * b.x + a.y * b.y + a.z * b.z + a.w * b.w;
  }
  for (int off = 32; off; off >>= 1) s += __shfl_down(s, off, 64);
  __shared__ float sm[4];
  if ((threadIdx.x & 63) == 0) sm[threadIdx.x >> 6] = s;
  __syncthreads();
  if (threadIdx.x == 0) xy[row] = sm[0] + sm[1] + sm[2] + sm[3] + bias[st];
}

// 256x128 block tile, 4 waves in 2x2; each wave 128x64 via 4x2 of 32x32x64.
// All operands loaded straight from global fragment chunks (no LDS staging).
// Epilogue: partials[bn][row] = sum_cols exp(logit + bias).
__global__ __launch_bounds__(256, 2)
void gemm_sumexp(const char* __restrict__ Xf, const char* __restrict__ Wf,
                 const float* __restrict__ bias, float* __restrict__ partials,
                 int H, int BT) {
  __shared__ float rowsum[2][256];

  const int tid = threadIdx.x;
  const int w = tid >> 6, lane = tid & 63;
  const int wr = w >> 1, wc = w & 1;
  const int l32 = lane & 31, kh = lane >> 5;
  const int m0 = blockIdx.x * 256, n0 = blockIdx.y * 128;

  f16v acc[4][2];
#pragma unroll
  for (int mi = 0; mi < 4; mi++)
#pragma unroll
    for (int ni = 0; ni < 2; ni++)
#pragma unroll
      for (int r = 0; r < 16; r++) acc[mi][ni][r] = 0.f;

  const int Rb = blockIdx.x * 8 + wr * 4;   // A 32-row block base
  const int Nb = blockIdx.y * 4 + wc * 2;   // B 32-row block base

  const char* pa[4];
  const char* pb[2];
#pragma unroll
  for (int mi = 0; mi < 4; mi++)
    pa[mi] = Xf + ((long)(Rb + mi) * 16) * 2048 + lane * 16;
#pragma unroll
  for (int ni = 0; ni < 2; ni++)
    pb[ni] = Wf + ((long)(Nb + ni) * 16) * 2048 + lane * 16;

  const int nG = H >> 6;  // 16 k-groups of 64
#pragma unroll 4
  for (int g = 0; g < nG; g++) {
    v8i a[4], b[2];
#pragma unroll
    for (int mi = 0; mi < 4; mi++) {
      int4 lo = *(const int4*)(pa[mi]);
      int4 hi = *(const int4*)(pa[mi] + 1024);
      v8i t;
      t[0] = lo.x; t[1] = lo.y; t[2] = lo.z; t[3] = lo.w;
      t[4] = hi.x; t[5] = hi.y; t[6] = hi.z; t[7] = hi.w;
      a[mi] = t;
      pa[mi] += 2048;
    }
#pragma unroll
    for (int ni = 0; ni < 2; ni++) {
      int4 lo = *(const int4*)(pb[ni]);
      int4 hi = *(const int4*)(pb[ni] + 1024);
      v8i t;
      t[0] = lo.x; t[1] = lo.y; t[2] = lo.z; t[3] = lo.w;
      t[4] = hi.x; t[5] = hi.y; t[6] = hi.z; t[7] = hi.w;
      b[ni] = t;
      pb[ni] += 2048;
    }
#pragma unroll
    for (int mi = 0; mi < 4; mi++)
#pragma unroll
      for (int ni = 0; ni < 2; ni++)
        acc[mi][ni] = __builtin_amdgcn_mfma_scale_f32_32x32x64_f8f6f4(
            a[mi], b[ni], acc[mi][ni], 0 /*A=fp8*/, 0 /*B=fp8*/,
            0, 127 /*scale_a = 1.0*/, 0, 127 /*scale_b = 1.0*/);
  }

  // ---- epilogue: per-row sum of exp(logit + bias) ----
  // C/D 32x32 layout: col = lane&31, row = (reg&3) + 8*(reg>>2) + 4*(lane>>5)
  float bv[2];
  bv[0] = bias[n0 + wc * 64 + l32];
  bv[1] = bias[n0 + wc * 64 + 32 + l32];

#pragma unroll
  for (int mi = 0; mi < 4; mi++) {
    float p[16];
#pragma unroll
    for (int r = 0; r < 16; r++) p[r] = 0.f;
#pragma unroll
    for (int ni = 0; ni < 2; ni++)
#pragma unroll
      for (int r = 0; r < 16; r++) p[r] += __expf(acc[mi][ni][r] + bv[ni]);
    // reduce across the 32 columns (lanes within each 32-group)
#pragma unroll
    for (int off = 1; off < 32; off <<= 1)
#pragma unroll
      for (int r = 0; r < 16; r++) p[r] += __shfl_xor(p[r], off, 32);
    if (l32 == 0) {
#pragma unroll
      for (int r = 0; r < 16; r++)
        rowsum[wc][wr * 128 + mi * 32 + (r & 3) + 8 * (r >> 2) + 4 * kh] = p[r];
    }
  }
  __syncthreads();
  partials[(long)blockIdx.y * BT + m0 + tid] = rowsum[0][tid] + rowsum[1][tid];
}

// per-row: lse - x_y ; block partial sums
__global__ __launch_bounds__(256)
void row_reduce(const float* __restrict__ partials, const float* __restrict__ xy,
                const int* __restrict__ tgt, float* __restrict__ bsum,
                float* __restrict__ bcnt, int BT, int nCB) {
  int row = blockIdx.x * 256 + threadIdx.x;
  float S = 0.f;
  for (int b = 0; b < nCB; b++) S += partials[(long)b * BT + row];
  int t = tgt[row];
  bool valid = (t != -100);
  float pr = valid ? (logf(S) - xy[row]) : 0.f;
  float c = valid ? 1.f : 0.f;
  for (int off = 32; off; off >>= 1) {
    pr += __shfl_down(pr, off, 64);
    c += __shfl_down(c, off, 64);
  }
  __shared__ float sp[4], sc[4];
  if ((threadIdx.x & 63) == 0) {
    sp[threadIdx.x >> 6] = pr;
    sc[threadIdx.x >> 6] = c;
  }
  __syncthreads();
  if (threadIdx.x == 0) {
    bsum[blockIdx.x] = sp[0] + sp[1] + sp[2] + sp[3];
    bcnt[blockIdx.x] = sc[0] + sc[1] + sc[2] + sc[3];
  }
}

__global__ void finalize(const float* __restrict__ bsum, const float* __restrict__ bcnt,
                         float* __restrict__ out, int nb) {
  float s = 0.f, c = 0.f;
  for (int i = threadIdx.x; i < nb; i += 64) { s += bsum[i]; c += bcnt[i]; }
  for (int off = 32; off; off >>= 1) {
    s += __shfl_down(s, off, 64);
    c += __shfl_down(c, off, 64);
  }
  if (threadIdx.x == 0) out[0] = s / c;
}

extern "C" void kernel_launch(void* const* d_in, const int* in_sizes, int n_in,
                              void* d_out, int out_size, void* d_ws, size_t ws_size,
                              hipStream_t stream) {
  const float* x = (const float*)d_in[0];
  const int* tgt = (const int*)d_in[1];
  const float* w = (const float*)d_in[2];
  const float* bias = (const float*)d_in[3];
  float* out = (float*)d_out;

  const int BT = in_sizes[1];            // 4096
  const int V = in_sizes[3];             // 32000
  const int H = in_sizes[0] / BT;        // 1024
  const int nCB = V / 128;               // 250 column blocks

  char* ws = (char*)d_ws;
  const long wb_bytes = (long)V * H;     // fp8: 1 B/elem
  const long xb_bytes = (long)BT * H;
  char* Wf = ws;
  char* Xf = ws + wb_bytes;
  float* partials = (float*)(ws + wb_bytes + xb_bytes);
  float* xy = partials + (long)nCB * BT;
  float* bsum = xy + BT;
  float* bcnt = bsum + (BT / 256);

  cast_swz_k<<<8192, 256, 0, stream>>>(w, (uint4*)Wf, (long)V * H / 16);
  cast_swz_k<<<1024, 256, 0, stream>>>(x, (uint4*)Xf, (long)BT * H / 16);
  xy_k<<<BT, 256, 0, stream>>>(x, w, bias, tgt, xy, H, V);
  // grid.x = row-blocks (fast-varying) so consecutive blocks share the W tile in L2
  dim3 grid(BT / 256, nCB);
  gemm_sumexp<<<grid, 256, 0, stream>>>(Xf, Wf, bias, partials, H, BT);
  row_reduce<<<BT / 256, 256, 0, stream>>>(partials, xy, tgt, bsum, bcnt, BT, nCB);
  finalize<<<1, 64, 0, stream>>>(bsum, bcnt, out, BT / 256);
}